// Round 1
// baseline (395.821 us; speedup 1.0000x reference)
//
#include <hip/hip_runtime.h>
#include <hip/hip_bf16.h>
#include <math.h>

#define Nn 20000
#define Ee 320000
#define INF_ 256
#define Hh 4
#define Cc 64
#define HC 256
#define NEG_SLOPE 0.2f

using frag16 = __attribute__((ext_vector_type(8))) short;   // 8 bf16 (4 VGPRs)
using f32x4  = __attribute__((ext_vector_type(4))) float;

// ---------------- CSR build ----------------

__global__ void init_deg(int* deg, int n) {
    int i = blockIdx.x * blockDim.x + threadIdx.x;
    if (i < n) deg[i] = 1;  // self-loop pre-counted
}

__global__ void hist_kernel(const int* __restrict__ dst, int ne, int* deg) {
    int e = blockIdx.x * blockDim.x + threadIdx.x;
    if (e < ne) atomicAdd(&deg[dst[e]], 1);
}

// hierarchical scan, phase 1: per-block (256 elems) exclusive scan + block sum
__global__ __launch_bounds__(256) void scan1(const int* __restrict__ deg,
                                             int* __restrict__ excl,
                                             int* __restrict__ bsum, int n) {
    int tid = threadIdx.x;
    int gid = blockIdx.x * 256 + tid;
    int lane = tid & 63;
    int v = (gid < n) ? deg[gid] : 0;
    int x = v;
    #pragma unroll
    for (int off = 1; off < 64; off <<= 1) {
        int y = __shfl_up(x, off, 64);
        if (lane >= off) x += y;
    }
    __shared__ int wsum[4];
    if (lane == 63) wsum[tid >> 6] = x;
    __syncthreads();
    int wadd = 0;
    for (int w = 0; w < (tid >> 6); ++w) wadd += wsum[w];
    int incl = x + wadd;
    if (gid < n) excl[gid] = incl - v;
    if (tid == 255) bsum[blockIdx.x] = incl;
}

// phase 2: single-wave scan over block sums (nb ~ 79 -> 2 iters)
__global__ void scan2(const int* __restrict__ bsum, int* __restrict__ boff, int nb) {
    int lane = threadIdx.x;
    int carry = 0;
    for (int base = 0; base < nb; base += 64) {
        int i = base + lane;
        int v = (i < nb) ? bsum[i] : 0;
        int x = v;
        #pragma unroll
        for (int off = 1; off < 64; off <<= 1) {
            int y = __shfl_up(x, off, 64);
            if (lane >= off) x += y;
        }
        if (i < nb) boff[i] = carry + x - v;
        carry += __shfl(x, 63, 64);
    }
    if (lane == 0) boff[nb] = carry;
}

// phase 3: add block offsets, produce row_start + cursor (+ total at [n])
__global__ void scan_add(int* __restrict__ row_start, int* __restrict__ cursor,
                         const int* __restrict__ boff, int n, int nb) {
    int gid = blockIdx.x * blockDim.x + threadIdx.x;
    if (gid < n) {
        int v = row_start[gid] + boff[gid >> 8];
        row_start[gid] = v;
        cursor[gid] = v;
    }
    if (gid == n) row_start[n] = boff[nb];
}

__global__ void scatter_kernel(const int* __restrict__ src, const int* __restrict__ dst,
                               int ne, int n, int* cursor, int* colx) {
    int e = blockIdx.x * blockDim.x + threadIdx.x;
    if (e < ne) {
        int d = dst[e];
        int pos = atomicAdd(&cursor[d], 1);
        colx[pos] = src[e];
    } else if (e < ne + n) {
        int node = e - ne;
        int pos = atomicAdd(&cursor[node], 1);
        colx[pos] = node;  // self-loop
    }
}

// ---------------- bf16 split-precision helpers ----------------

__device__ inline unsigned short bf16rn(float f) {
    unsigned u = __float_as_uint(f);
    unsigned r = (u + 0x7FFFu + ((u >> 16) & 1u)) >> 16;   // RTNE
    return (unsigned short)r;
}

__device__ inline void split1(float v, short& h, short& l) {
    unsigned short hh = bf16rn(v);
    float back = __uint_as_float(((unsigned)hh) << 16);
    unsigned short ll = bf16rn(v - back);
    h = (short)hh; l = (short)ll;
}

__device__ __forceinline__ float4 bf4_to_f4(ushort4 u) {
    return make_float4(__uint_as_float((unsigned)u.x << 16),
                       __uint_as_float((unsigned)u.y << 16),
                       __uint_as_float((unsigned)u.z << 16),
                       __uint_as_float((unsigned)u.w << 16));
}

// fp32 M x 256 -> hi/lo bf16 (same layout), 4 elems/thread (layer-1 x only)
__global__ __launch_bounds__(256) void split_kernel(const float* __restrict__ in,
                                                    short* __restrict__ hi,
                                                    short* __restrict__ lo, int n4) {
    int i = blockIdx.x * blockDim.x + threadIdx.x;
    if (i >= n4) return;
    float4 v = ((const float4*)in)[i];
    short4 h, l;
    split1(v.x, h.x, l.x);
    split1(v.y, h.y, l.y);
    split1(v.z, h.z, l.z);
    split1(v.w, h.w, l.w);
    ((short4*)hi)[i] = h;
    ((short4*)lo)[i] = l;
}

// all 4 weight matrices (K=256 x N=256 fp32) -> transposed split, one dispatch.
__global__ __launch_bounds__(256) void wsplit_all(const float* __restrict__ Wl1,
                                                  const float* __restrict__ Wr1,
                                                  const float* __restrict__ Wl2,
                                                  const float* __restrict__ Wr2,
                                                  short* __restrict__ WhT1,
                                                  short* __restrict__ WlT1,
                                                  short* __restrict__ WhT2,
                                                  short* __restrict__ WlT2) {
    int b = blockIdx.x;
    int n = b & 255;
    int k = threadIdx.x;
    const float* W = (b < 256) ? Wl1 : (b < 512) ? Wr1 : (b < 768) ? Wl2 : Wr2;
    short* Wh = (b < 512) ? WhT1 : WhT2;
    short* Wl = (b < 512) ? WlT1 : WlT2;
    int col = b & 511;                  // concat col within layer
    float v = W[k * 256 + n];
    short h, l;
    split1(v, h, l);
    Wh[col * 256 + k] = h;
    Wl[col * 256 + k] = l;
}

// ---------------- bf16x3 MFMA fused GEMM, LDS-free / barrier-free ----------
// [XL | XR] = A @ [Wl | Wr],  C = Ah*Wh + Al*Wh + Ah*Wl (bf16x3 split).
// Each MFMA fragment (8 contiguous k-elements per lane) is contiguous in
// global memory, so fragments are loaded directly global->VGPR:
//   - no LDS, no __syncthreads, no vmcnt(0) barrier drains, no bank conflicts
//   - waves fully independent; compiler free to pipeline loads under MFMAs
// B (512 KB for both hi/lo) is shared by all 157 row-blocks -> L2-resident.
// A (20.5 MB hi+lo) is re-read across the 4 col-groups but L3-resident.
// XL written as bf16-hi only; XR fp32 (same as before).

__global__ __launch_bounds__(256) void mfma_gemm(const short* __restrict__ Ah,
                                                 const short* __restrict__ Al,
                                                 const short* __restrict__ WhT,
                                                 const short* __restrict__ WlT,
                                                 unsigned short* __restrict__ XLh,
                                                 float* __restrict__ XR) {
    int tid = threadIdx.x;
    int wave = tid >> 6, lane = tid & 63;
    int quad = lane >> 4, lc = lane & 15;
    int bx = blockIdx.y;                 // 0..3: concat col group (128 cols)
    int bm = blockIdx.x * 128;           // row group
    int cbase = (bx * 128) & 255;

    // A rows this wave owns (two 16-row sub-tiles); clamp tail rows
    int row0 = bm + wave * 32 + lc;
    int row1 = row0 + 16;
    int ca0 = (row0 < Nn) ? row0 : (Nn - 1);
    int ca1 = (row1 < Nn) ? row1 : (Nn - 1);

    const short* pa0h = Ah  + (size_t)ca0 * HC + quad * 8;
    const short* pa1h = Ah  + (size_t)ca1 * HC + quad * 8;
    const short* pa0l = Al  + (size_t)ca0 * HC + quad * 8;
    const short* pa1l = Al  + (size_t)ca1 * HC + quad * 8;
    const short* pbh  = WhT + (size_t)(bx * 128 + lc) * HC + quad * 8;
    const short* pbl  = WlT + (size_t)(bx * 128 + lc) * HC + quad * 8;

    f32x4 acc[2][8] = {};
    for (int c = 0; c < 8; ++c) {
        int k0 = c * 32;
        frag16 a0h = *(const frag16*)(pa0h + k0);
        frag16 a1h = *(const frag16*)(pa1h + k0);
        frag16 a0l = *(const frag16*)(pa0l + k0);
        frag16 a1l = *(const frag16*)(pa1l + k0);
        #pragma unroll
        for (int t = 0; t < 8; ++t) {
            frag16 bh = *(const frag16*)(pbh + (size_t)t * 16 * HC + k0);
            frag16 bl = *(const frag16*)(pbl + (size_t)t * 16 * HC + k0);
            acc[0][t] = __builtin_amdgcn_mfma_f32_16x16x32_bf16(a0h, bh, acc[0][t], 0, 0, 0);
            acc[1][t] = __builtin_amdgcn_mfma_f32_16x16x32_bf16(a1h, bh, acc[1][t], 0, 0, 0);
            acc[0][t] = __builtin_amdgcn_mfma_f32_16x16x32_bf16(a0l, bh, acc[0][t], 0, 0, 0);
            acc[1][t] = __builtin_amdgcn_mfma_f32_16x16x32_bf16(a1l, bh, acc[1][t], 0, 0, 0);
            acc[0][t] = __builtin_amdgcn_mfma_f32_16x16x32_bf16(a0h, bl, acc[0][t], 0, 0, 0);
            acc[1][t] = __builtin_amdgcn_mfma_f32_16x16x32_bf16(a1h, bl, acc[1][t], 0, 0, 0);
        }
    }
    #pragma unroll
    for (int mt = 0; mt < 2; ++mt) {
        int rbase = bm + wave * 32 + mt * 16 + quad * 4;
        #pragma unroll
        for (int t = 0; t < 8; ++t) {
            int col = cbase + t * 16 + lc;
            #pragma unroll
            for (int r = 0; r < 4; ++r) {
                int rw = rbase + r;
                if (rw >= Nn) continue;
                if (bx < 2) XLh[(size_t)rw * HC + col] = bf16rn(acc[mt][t][r]);
                else        XR [(size_t)rw * HC + col] = acc[mt][t][r];
            }
        }
    }
}

// ---------------- GATv2 edge phase ----------------
// One wave per node (4 nodes/block). Lane holds 4 channels; head h = lanes
// 16h..16h+15. XL gathered in bf16 (8 B/lane); XR/bias fp32.
// No-max softmax (scores bounded << 88); leaky(t)=0.6t+0.4|t|.
// 2-way edge unroll w/ independent partials for memory-level parallelism.
// mode 1: also write bf16 hi/lo split of relu(h) for next layer's GEMM.

__device__ __forceinline__ float edge_score(const float4 v, const float4 xr,
                                            const float4 a06, const float4 a04) {
    float tx = v.x + xr.x, ty = v.y + xr.y, tz = v.z + xr.z, tw = v.w + xr.w;
    float p = a06.x * tx + a04.x * fabsf(tx);
    p += a06.y * ty + a04.y * fabsf(ty);
    p += a06.z * tz + a04.z * fabsf(tz);
    p += a06.w * tw + a04.w * fabsf(tw);
    p += __shfl_xor(p, 1, 64);
    p += __shfl_xor(p, 2, 64);
    p += __shfl_xor(p, 4, 64);
    p += __shfl_xor(p, 8, 64);             // per-head score in its 16 lanes
    return p;
}

__global__ __launch_bounds__(256) void gat_kernel(const ushort4* __restrict__ XL4,
                                                  const float4* __restrict__ XR4,
                                                  const int* __restrict__ row_start,
                                                  const int* __restrict__ colx,
                                                  const float4* __restrict__ att4,
                                                  const float4* __restrict__ bias4,
                                                  float4* __restrict__ Hout,
                                                  short4* __restrict__ Ahi,
                                                  short4* __restrict__ Alo,
                                                  int mode) {
    int wave = threadIdx.x >> 6, lane = threadIdx.x & 63;
    int node = blockIdx.x * 4 + wave;          // grid = Nn/4 exactly
    float4 xr = XR4[(size_t)node * 64 + lane];
    float4 a  = att4[lane];
    float4 a06 = make_float4(a.x * 0.6f, a.y * 0.6f, a.z * 0.6f, a.w * 0.6f);
    float4 a04 = make_float4(a.x * 0.4f, a.y * 0.4f, a.z * 0.4f, a.w * 0.4f);
    int e0 = row_start[node], e1 = row_start[node + 1];
    float l0 = 0.f, l1 = 0.f;
    float4 acc0 = make_float4(0.f, 0.f, 0.f, 0.f);
    float4 acc1 = make_float4(0.f, 0.f, 0.f, 0.f);
    int e = e0;
    for (; e + 1 < e1; e += 2) {
        int s0 = __builtin_amdgcn_readfirstlane(colx[e]);
        int s1 = __builtin_amdgcn_readfirstlane(colx[e + 1]);
        ushort4 u0 = XL4[(size_t)s0 * 64 + lane];
        ushort4 u1 = XL4[(size_t)s1 * 64 + lane];
        float4 v0 = bf4_to_f4(u0);
        float4 v1 = bf4_to_f4(u1);
        float pe0 = __expf(edge_score(v0, xr, a06, a04));
        float pe1 = __expf(edge_score(v1, xr, a06, a04));
        l0 += pe0; l1 += pe1;
        acc0.x += pe0 * v0.x; acc0.y += pe0 * v0.y;
        acc0.z += pe0 * v0.z; acc0.w += pe0 * v0.w;
        acc1.x += pe1 * v1.x; acc1.y += pe1 * v1.y;
        acc1.z += pe1 * v1.z; acc1.w += pe1 * v1.w;
    }
    if (e < e1) {
        int s0 = __builtin_amdgcn_readfirstlane(colx[e]);
        float4 v0 = bf4_to_f4(XL4[(size_t)s0 * 64 + lane]);
        float pe0 = __expf(edge_score(v0, xr, a06, a04));
        l0 += pe0;
        acc0.x += pe0 * v0.x; acc0.y += pe0 * v0.y;
        acc0.z += pe0 * v0.z; acc0.w += pe0 * v0.w;
    }
    float rl = 1.f / (l0 + l1);
    float4 b = bias4[lane];
    float4 o = make_float4(fmaxf((acc0.x + acc1.x) * rl + b.x, 0.f),
                           fmaxf((acc0.y + acc1.y) * rl + b.y, 0.f),
                           fmaxf((acc0.z + acc1.z) * rl + b.z, 0.f),
                           fmaxf((acc0.w + acc1.w) * rl + b.w, 0.f));
    size_t oidx = (size_t)node * 64 + lane;
    if (mode) {
        short4 h4, l4;
        split1(o.x, h4.x, l4.x);
        split1(o.y, h4.y, l4.y);
        split1(o.z, h4.z, l4.z);
        split1(o.w, h4.w, l4.w);
        Ahi[oidx] = h4;
        Alo[oidx] = l4;
    } else {
        Hout[oidx] = o;
    }
}

// ---------------- pooling + FC ----------------

__global__ void zero_f(float* p, int n) {
    int i = blockIdx.x * blockDim.x + threadIdx.x;
    if (i < n) p[i] = 0.f;
}

__global__ __launch_bounds__(256) void colsum_kernel(const float* __restrict__ Hmat,
                                                     float* __restrict__ g, int n) {
    int ch = threadIdx.x;
    float s = 0.f;
    for (int r = blockIdx.x; r < n; r += gridDim.x)
        s += Hmat[(size_t)r * HC + ch];
    atomicAdd(&g[ch], s);
}

__global__ __launch_bounds__(256) void fc_kernel(const float* __restrict__ g,
                                                 const float* __restrict__ Wfc,
                                                 const float* __restrict__ bfc,
                                                 float* __restrict__ out, float invN) {
    int t = threadIdx.x;
    float gv = g[t] * invN;
    float p0 = gv * Wfc[2 * t];
    float p1 = gv * Wfc[2 * t + 1];
    #pragma unroll
    for (int off = 32; off > 0; off >>= 1) {
        p0 += __shfl_xor(p0, off, 64);
        p1 += __shfl_xor(p1, off, 64);
    }
    __shared__ float s0[4], s1[4];
    if ((t & 63) == 0) { s0[t >> 6] = p0; s1[t >> 6] = p1; }
    __syncthreads();
    if (t == 0) {
        out[0] = s0[0] + s0[1] + s0[2] + s0[3] + bfc[0];
        out[1] = s1[0] + s1[1] + s1[2] + s1[3] + bfc[1];
    }
}

// ---------------- launch ----------------

extern "C" void kernel_launch(void* const* d_in, const int* in_sizes, int n_in,
                              void* d_out, int out_size, void* d_ws, size_t ws_size,
                              hipStream_t stream) {
    const float* x    = (const float*)d_in[0];
    const int*   eidx = (const int*)d_in[1];   // (2,E) row-major: [src | dst]
    const float* Wl1  = (const float*)d_in[2];
    const float* Wr1  = (const float*)d_in[3];
    const float* att1 = (const float*)d_in[4];
    const float* b1   = (const float*)d_in[5];
    const float* Wl2  = (const float*)d_in[6];
    const float* Wr2  = (const float*)d_in[7];
    const float* att2 = (const float*)d_in[8];
    const float* b2   = (const float*)d_in[9];
    const float* Wfc  = (const float*)d_in[10];
    const float* bfc  = (const float*)d_in[11];
    float* out = (float*)d_out;

    const int* srcv = eidx;
    const int* dstv = eidx + Ee;

    // workspace layout (~75 MB)
    size_t NHC = (size_t)Nn * HC;
    float* XR = (float*)d_ws;
    float* Hb = XR + NHC;
    float* g  = Hb + NHC;
    unsigned short* XLh = (unsigned short*)(g + HC);
    short* Ah   = (short*)(XLh + NHC);
    short* Al   = Ah + NHC;
    short* WhT1 = Al + NHC;                    // 512*256 concat [Wl|Wr]^T per layer
    short* WlT1 = WhT1 + 512 * 256;
    short* WhT2 = WlT1 + 512 * 256;
    short* WlT2 = WhT2 + 512 * 256;
    int* deg       = (int*)(WlT2 + 512 * 256);
    int* row_start = deg + Nn;
    int* cursor    = row_start + (Nn + 1);
    int* colx      = cursor + Nn;              // Ee + Nn entries
    int* bsum      = colx + (Ee + Nn);
    int* boff      = bsum + 128;               // NB+1 entries

    const int NB = (Nn + 255) / 256;           // 79
    const int N4 = (int)(NHC / 4);

    // CSR build
    init_deg<<<(Nn + 255) / 256, 256, 0, stream>>>(deg, Nn);
    hist_kernel<<<(Ee + 255) / 256, 256, 0, stream>>>(dstv, Ee, deg);
    scan1<<<NB, 256, 0, stream>>>(deg, row_start, bsum, Nn);
    scan2<<<1, 64, 0, stream>>>(bsum, boff, NB);
    scan_add<<<(Nn + 256) / 256, 256, 0, stream>>>(row_start, cursor, boff, Nn, NB);
    scatter_kernel<<<(Ee + Nn + 255) / 256, 256, 0, stream>>>(srcv, dstv, Ee, Nn, cursor, colx);

    dim3 ggrid((Nn + 127) / 128, 4);           // 157 x 4 (row-major rows first)

    // weight prep (both layers, one dispatch) + layer-1 input split
    wsplit_all<<<1024, 256, 0, stream>>>(Wl1, Wr1, Wl2, Wr2, WhT1, WlT1, WhT2, WlT2);
    split_kernel<<<(N4 + 255) / 256, 256, 0, stream>>>(x, Ah, Al, N4);

    // layer 1 (gat writes bf16 split directly -> layer-2 GEMM input)
    mfma_gemm<<<ggrid, 256, 0, stream>>>(Ah, Al, WhT1, WlT1, XLh, XR);
    gat_kernel<<<Nn / 4, 256, 0, stream>>>((const ushort4*)XLh, (const float4*)XR,
                                           row_start, colx, (const float4*)att1,
                                           (const float4*)b1, (float4*)Hb,
                                           (short4*)Ah, (short4*)Al, 1);

    // layer 2
    mfma_gemm<<<ggrid, 256, 0, stream>>>(Ah, Al, WhT2, WlT2, XLh, XR);
    gat_kernel<<<Nn / 4, 256, 0, stream>>>((const ushort4*)XLh, (const float4*)XR,
                                           row_start, colx, (const float4*)att2,
                                           (const float4*)b2, (float4*)Hb,
                                           (short4*)Ah, (short4*)Al, 0);

    // pool + fc
    zero_f<<<1, 256, 0, stream>>>(g, HC);
    colsum_kernel<<<256, 256, 0, stream>>>(Hb, g, Nn);
    fc_kernel<<<1, 256, 0, stream>>>(g, Wfc, bfc, out, 1.0f / Nn);
}

// Round 2
// 293.140 us; speedup vs baseline: 1.3503x; 1.3503x over previous
//
#include <hip/hip_runtime.h>
#include <hip/hip_bf16.h>
#include <math.h>

#define Nn 20000
#define Ee 320000
#define INF_ 256
#define Hh 4
#define Cc 64
#define HC 256
#define NEG_SLOPE 0.2f

using frag16 = __attribute__((ext_vector_type(8))) short;   // 8 bf16 (4 VGPRs)
using f32x4  = __attribute__((ext_vector_type(4))) float;

// async global->LDS 16B per lane; LDS dest = wave-uniform base + lane*16
__device__ __forceinline__ void async16(const void* g, void* l) {
    __builtin_amdgcn_global_load_lds(
        (const __attribute__((address_space(1))) unsigned int*)g,
        (__attribute__((address_space(3))) unsigned int*)l,
        16, 0, 0);
}

// ---------------- CSR build ----------------

__global__ void init_deg(int* deg, int n) {
    int i = blockIdx.x * blockDim.x + threadIdx.x;
    if (i < n) deg[i] = 1;  // self-loop pre-counted
}

__global__ void hist_kernel(const int* __restrict__ dst, int ne, int* deg) {
    int e = blockIdx.x * blockDim.x + threadIdx.x;
    if (e < ne) atomicAdd(&deg[dst[e]], 1);
}

// hierarchical scan, phase 1: per-block (256 elems) exclusive scan + block sum
__global__ __launch_bounds__(256) void scan1(const int* __restrict__ deg,
                                             int* __restrict__ excl,
                                             int* __restrict__ bsum, int n) {
    int tid = threadIdx.x;
    int gid = blockIdx.x * 256 + tid;
    int lane = tid & 63;
    int v = (gid < n) ? deg[gid] : 0;
    int x = v;
    #pragma unroll
    for (int off = 1; off < 64; off <<= 1) {
        int y = __shfl_up(x, off, 64);
        if (lane >= off) x += y;
    }
    __shared__ int wsum[4];
    if (lane == 63) wsum[tid >> 6] = x;
    __syncthreads();
    int wadd = 0;
    for (int w = 0; w < (tid >> 6); ++w) wadd += wsum[w];
    int incl = x + wadd;
    if (gid < n) excl[gid] = incl - v;
    if (tid == 255) bsum[blockIdx.x] = incl;
}

// phase 2: single-wave scan over block sums (nb ~ 79 -> 2 iters)
__global__ void scan2(const int* __restrict__ bsum, int* __restrict__ boff, int nb) {
    int lane = threadIdx.x;
    int carry = 0;
    for (int base = 0; base < nb; base += 64) {
        int i = base + lane;
        int v = (i < nb) ? bsum[i] : 0;
        int x = v;
        #pragma unroll
        for (int off = 1; off < 64; off <<= 1) {
            int y = __shfl_up(x, off, 64);
            if (lane >= off) x += y;
        }
        if (i < nb) boff[i] = carry + x - v;
        carry += __shfl(x, 63, 64);
    }
    if (lane == 0) boff[nb] = carry;
}

// phase 3: add block offsets, produce row_start + cursor (+ total at [n])
__global__ void scan_add(int* __restrict__ row_start, int* __restrict__ cursor,
                         const int* __restrict__ boff, int n, int nb) {
    int gid = blockIdx.x * blockDim.x + threadIdx.x;
    if (gid < n) {
        int v = row_start[gid] + boff[gid >> 8];
        row_start[gid] = v;
        cursor[gid] = v;
    }
    if (gid == n) row_start[n] = boff[nb];
}

__global__ void scatter_kernel(const int* __restrict__ src, const int* __restrict__ dst,
                               int ne, int n, int* cursor, int* colx) {
    int e = blockIdx.x * blockDim.x + threadIdx.x;
    if (e < ne) {
        int d = dst[e];
        int pos = atomicAdd(&cursor[d], 1);
        colx[pos] = src[e];
    } else if (e < ne + n) {
        int node = e - ne;
        int pos = atomicAdd(&cursor[node], 1);
        colx[pos] = node;  // self-loop
    }
}

// ---------------- bf16 split-precision helpers ----------------

__device__ inline unsigned short bf16rn(float f) {
    unsigned u = __float_as_uint(f);
    unsigned r = (u + 0x7FFFu + ((u >> 16) & 1u)) >> 16;   // RTNE
    return (unsigned short)r;
}

__device__ inline void split1(float v, short& h, short& l) {
    unsigned short hh = bf16rn(v);
    float back = __uint_as_float(((unsigned)hh) << 16);
    unsigned short ll = bf16rn(v - back);
    h = (short)hh; l = (short)ll;
}

__device__ __forceinline__ float4 bf4_to_f4(ushort4 u) {
    return make_float4(__uint_as_float((unsigned)u.x << 16),
                       __uint_as_float((unsigned)u.y << 16),
                       __uint_as_float((unsigned)u.z << 16),
                       __uint_as_float((unsigned)u.w << 16));
}

// fp32 M x 256 -> hi/lo bf16 (same layout), 4 elems/thread (layer-1 x only)
__global__ __launch_bounds__(256) void split_kernel(const float* __restrict__ in,
                                                    short* __restrict__ hi,
                                                    short* __restrict__ lo, int n4) {
    int i = blockIdx.x * blockDim.x + threadIdx.x;
    if (i >= n4) return;
    float4 v = ((const float4*)in)[i];
    short4 h, l;
    split1(v.x, h.x, l.x);
    split1(v.y, h.y, l.y);
    split1(v.z, h.z, l.z);
    split1(v.w, h.w, l.w);
    ((short4*)hi)[i] = h;
    ((short4*)lo)[i] = l;
}

// all 4 weight matrices (K=256 x N=256 fp32) -> transposed split, one dispatch.
__global__ __launch_bounds__(256) void wsplit_all(const float* __restrict__ Wl1,
                                                  const float* __restrict__ Wr1,
                                                  const float* __restrict__ Wl2,
                                                  const float* __restrict__ Wr2,
                                                  short* __restrict__ WhT1,
                                                  short* __restrict__ WlT1,
                                                  short* __restrict__ WhT2,
                                                  short* __restrict__ WlT2) {
    int b = blockIdx.x;
    int n = b & 255;
    int k = threadIdx.x;
    const float* W = (b < 256) ? Wl1 : (b < 512) ? Wr1 : (b < 768) ? Wl2 : Wr2;
    short* Wh = (b < 512) ? WhT1 : WhT2;
    short* Wl = (b < 512) ? WlT1 : WlT2;
    int col = b & 511;                  // concat col within layer
    float v = W[k * 256 + n];
    short h, l;
    split1(v, h, l);
    Wh[col * 256 + k] = h;
    Wl[col * 256 + k] = l;
}

// ---------------- bf16x3 MFMA fused GEMM, single-barrier hybrid -------------
// [XL | XR] = A @ [Wl | Wr],  C = Ah*Wh + Al*Wh + Ah*Wl (bf16x3 split).
//
// Structure (fixes round-0's 16 barrier-drains AND round-1's serial loads):
//  - B (64-col group, full K=256, hi+lo = 64 KB) staged into LDS ONCE,
//    then ONE __syncthreads. Zero barriers in the K-loop.
//  - B LDS is [col][k-chunk] (512 B col stride) with XOR swizzle
//    chunk ^= (col&7), applied via per-lane PRE-SWIZZLED GLOBAL source of
//    global_load_lds (LDS dest stays linear) and the same XOR on ds_read.
//    Without it the 16-lane ds_read_b128 would be 16-way bank-conflicted.
//  - A fragments loaded direct global->VGPR (each wave reads only its own
//    rows; fragments are 16 B contiguous). K-loop fully unrolled so the
//    compiler pipelines the 4 A-loads/step across the straight-line body.
//  - XCD remap: 8 col-group blocks sharing an A row-tile run consecutively
//    on the SAME XCD -> A fetched from HBM once, re-read from local L2.

__global__ __launch_bounds__(256) void mfma_gemm(const short* __restrict__ Ah,
                                                 const short* __restrict__ Al,
                                                 const short* __restrict__ WhT,
                                                 const short* __restrict__ WlT,
                                                 unsigned short* __restrict__ XLh,
                                                 float* __restrict__ XR) {
    __shared__ short BsH[64 * 256];
    __shared__ short BsL[64 * 256];

    int tid = threadIdx.x;
    int wave = tid >> 6, lane = tid & 63;
    int quad = lane >> 4, lc = lane & 15;

    // XCD-aware remap: hw round-robins blockIdx%8 across XCDs. Give XCD x the
    // contiguous pair-range [x*157, (x+1)*157): row-major over (row_tile, colg)
    // so all 8 col-groups of a row-tile land on one XCD back-to-back.
    int v = blockIdx.x;                 // 0..1255
    int p = (v & 7) * 157 + (v >> 3);
    int rowt = p >> 3;                  // 0..156
    int colg = p & 7;                   // 0..7: 64-col group of [Wl|Wr]
    int bm = rowt * 128;
    int cbase = (colg * 64) & 255;

    // ---- stage B (hi+lo) once: 8 rounds x (hi,lo), 4 KB per round ----
    {
        int cl0 = wave * 2 + (lane >> 5);          // col_local base (0..7)
        int kcs = (lane & 31) ^ (cl0 & 7);         // pre-swizzled source chunk
        const short* srcH = WhT + (size_t)(colg * 64 + cl0) * HC + kcs * 8;
        const short* srcL = WlT + (size_t)(colg * 64 + cl0) * HC + kcs * 8;
        short* dstH = &BsH[wave * 512];
        short* dstL = &BsL[wave * 512];
        #pragma unroll
        for (int r = 0; r < 8; ++r) {
            async16(srcH + (size_t)r * 8 * HC, dstH + r * 2048);
            async16(srcL + (size_t)r * 8 * HC, dstL + r * 2048);
        }
    }

    // A rows this wave owns (two 16-row sub-tiles); clamp tail rows
    int row0 = bm + wave * 32 + lc;
    int row1 = row0 + 16;
    int ca0 = (row0 < Nn) ? row0 : (Nn - 1);
    int ca1 = (row1 < Nn) ? row1 : (Nn - 1);
    const short* pa0h = Ah + (size_t)ca0 * HC + quad * 8;
    const short* pa1h = Ah + (size_t)ca1 * HC + quad * 8;
    const short* pa0l = Al + (size_t)ca0 * HC + quad * 8;
    const short* pa1l = Al + (size_t)ca1 * HC + quad * 8;

    __syncthreads();   // drains the 16 staging loads (vmcnt(0)) -- only barrier

    f32x4 acc[2][4] = {};
    #pragma unroll
    for (int c = 0; c < 8; ++c) {
        int k0 = c * 32;
        frag16 a0h = *(const frag16*)(pa0h + k0);
        frag16 a1h = *(const frag16*)(pa1h + k0);
        frag16 a0l = *(const frag16*)(pa0l + k0);
        frag16 a1l = *(const frag16*)(pa1l + k0);
        int sw = ((c * 4 + quad) ^ (lc & 7)) * 8;   // swizzled k-chunk (shorts)
        #pragma unroll
        for (int t = 0; t < 4; ++t) {
            int colL = t * 16 + lc;
            frag16 bh = *(const frag16*)&BsH[colL * HC + sw];
            frag16 bl = *(const frag16*)&BsL[colL * HC + sw];
            acc[0][t] = __builtin_amdgcn_mfma_f32_16x16x32_bf16(a0h, bh, acc[0][t], 0, 0, 0);
            acc[1][t] = __builtin_amdgcn_mfma_f32_16x16x32_bf16(a1h, bh, acc[1][t], 0, 0, 0);
            acc[0][t] = __builtin_amdgcn_mfma_f32_16x16x32_bf16(a0l, bh, acc[0][t], 0, 0, 0);
            acc[1][t] = __builtin_amdgcn_mfma_f32_16x16x32_bf16(a1l, bh, acc[1][t], 0, 0, 0);
            acc[0][t] = __builtin_amdgcn_mfma_f32_16x16x32_bf16(a0h, bl, acc[0][t], 0, 0, 0);
            acc[1][t] = __builtin_amdgcn_mfma_f32_16x16x32_bf16(a1h, bl, acc[1][t], 0, 0, 0);
        }
    }

    #pragma unroll
    for (int mt = 0; mt < 2; ++mt) {
        int rbase = bm + wave * 32 + mt * 16 + quad * 4;
        #pragma unroll
        for (int t = 0; t < 4; ++t) {
            int col = cbase + t * 16 + lc;
            #pragma unroll
            for (int r = 0; r < 4; ++r) {
                int rw = rbase + r;
                if (rw >= Nn) continue;
                if (colg < 4) XLh[(size_t)rw * HC + col] = bf16rn(acc[mt][t][r]);
                else          XR [(size_t)rw * HC + col] = acc[mt][t][r];
            }
        }
    }
}

// ---------------- GATv2 edge phase ----------------
// One wave per node (4 nodes/block). Lane holds 4 channels; head h = lanes
// 16h..16h+15. XL gathered in bf16 (8 B/lane); XR/bias fp32.
// No-max softmax (scores bounded << 88); leaky(t)=0.6t+0.4|t|.
// 2-way edge unroll w/ independent partials for memory-level parallelism.
// mode 1: also write bf16 hi/lo split of relu(h) for next layer's GEMM.

__device__ __forceinline__ float edge_score(const float4 v, const float4 xr,
                                            const float4 a06, const float4 a04) {
    float tx = v.x + xr.x, ty = v.y + xr.y, tz = v.z + xr.z, tw = v.w + xr.w;
    float p = a06.x * tx + a04.x * fabsf(tx);
    p += a06.y * ty + a04.y * fabsf(ty);
    p += a06.z * tz + a04.z * fabsf(tz);
    p += a06.w * tw + a04.w * fabsf(tw);
    p += __shfl_xor(p, 1, 64);
    p += __shfl_xor(p, 2, 64);
    p += __shfl_xor(p, 4, 64);
    p += __shfl_xor(p, 8, 64);             // per-head score in its 16 lanes
    return p;
}

__global__ __launch_bounds__(256) void gat_kernel(const ushort4* __restrict__ XL4,
                                                  const float4* __restrict__ XR4,
                                                  const int* __restrict__ row_start,
                                                  const int* __restrict__ colx,
                                                  const float4* __restrict__ att4,
                                                  const float4* __restrict__ bias4,
                                                  float4* __restrict__ Hout,
                                                  short4* __restrict__ Ahi,
                                                  short4* __restrict__ Alo,
                                                  int mode) {
    int wave = threadIdx.x >> 6, lane = threadIdx.x & 63;
    int node = blockIdx.x * 4 + wave;          // grid = Nn/4 exactly
    float4 xr = XR4[(size_t)node * 64 + lane];
    float4 a  = att4[lane];
    float4 a06 = make_float4(a.x * 0.6f, a.y * 0.6f, a.z * 0.6f, a.w * 0.6f);
    float4 a04 = make_float4(a.x * 0.4f, a.y * 0.4f, a.z * 0.4f, a.w * 0.4f);
    int e0 = row_start[node], e1 = row_start[node + 1];
    float l0 = 0.f, l1 = 0.f;
    float4 acc0 = make_float4(0.f, 0.f, 0.f, 0.f);
    float4 acc1 = make_float4(0.f, 0.f, 0.f, 0.f);
    int e = e0;
    for (; e + 1 < e1; e += 2) {
        int s0 = __builtin_amdgcn_readfirstlane(colx[e]);
        int s1 = __builtin_amdgcn_readfirstlane(colx[e + 1]);
        ushort4 u0 = XL4[(size_t)s0 * 64 + lane];
        ushort4 u1 = XL4[(size_t)s1 * 64 + lane];
        float4 v0 = bf4_to_f4(u0);
        float4 v1 = bf4_to_f4(u1);
        float pe0 = __expf(edge_score(v0, xr, a06, a04));
        float pe1 = __expf(edge_score(v1, xr, a06, a04));
        l0 += pe0; l1 += pe1;
        acc0.x += pe0 * v0.x; acc0.y += pe0 * v0.y;
        acc0.z += pe0 * v0.z; acc0.w += pe0 * v0.w;
        acc1.x += pe1 * v1.x; acc1.y += pe1 * v1.y;
        acc1.z += pe1 * v1.z; acc1.w += pe1 * v1.w;
    }
    if (e < e1) {
        int s0 = __builtin_amdgcn_readfirstlane(colx[e]);
        float4 v0 = bf4_to_f4(XL4[(size_t)s0 * 64 + lane]);
        float pe0 = __expf(edge_score(v0, xr, a06, a04));
        l0 += pe0;
        acc0.x += pe0 * v0.x; acc0.y += pe0 * v0.y;
        acc0.z += pe0 * v0.z; acc0.w += pe0 * v0.w;
    }
    float rl = 1.f / (l0 + l1);
    float4 b = bias4[lane];
    float4 o = make_float4(fmaxf((acc0.x + acc1.x) * rl + b.x, 0.f),
                           fmaxf((acc0.y + acc1.y) * rl + b.y, 0.f),
                           fmaxf((acc0.z + acc1.z) * rl + b.z, 0.f),
                           fmaxf((acc0.w + acc1.w) * rl + b.w, 0.f));
    size_t oidx = (size_t)node * 64 + lane;
    if (mode) {
        short4 h4, l4;
        split1(o.x, h4.x, l4.x);
        split1(o.y, h4.y, l4.y);
        split1(o.z, h4.z, l4.z);
        split1(o.w, h4.w, l4.w);
        Ahi[oidx] = h4;
        Alo[oidx] = l4;
    } else {
        Hout[oidx] = o;
    }
}

// ---------------- pooling + FC ----------------

__global__ void zero_f(float* p, int n) {
    int i = blockIdx.x * blockDim.x + threadIdx.x;
    if (i < n) p[i] = 0.f;
}

__global__ __launch_bounds__(256) void colsum_kernel(const float* __restrict__ Hmat,
                                                     float* __restrict__ g, int n) {
    int ch = threadIdx.x;
    float s = 0.f;
    for (int r = blockIdx.x; r < n; r += gridDim.x)
        s += Hmat[(size_t)r * HC + ch];
    atomicAdd(&g[ch], s);
}

__global__ __launch_bounds__(256) void fc_kernel(const float* __restrict__ g,
                                                 const float* __restrict__ Wfc,
                                                 const float* __restrict__ bfc,
                                                 float* __restrict__ out, float invN) {
    int t = threadIdx.x;
    float gv = g[t] * invN;
    float p0 = gv * Wfc[2 * t];
    float p1 = gv * Wfc[2 * t + 1];
    #pragma unroll
    for (int off = 32; off > 0; off >>= 1) {
        p0 += __shfl_xor(p0, off, 64);
        p1 += __shfl_xor(p1, off, 64);
    }
    __shared__ float s0[4], s1[4];
    if ((t & 63) == 0) { s0[t >> 6] = p0; s1[t >> 6] = p1; }
    __syncthreads();
    if (t == 0) {
        out[0] = s0[0] + s0[1] + s0[2] + s0[3] + bfc[0];
        out[1] = s1[0] + s1[1] + s1[2] + s1[3] + bfc[1];
    }
}

// ---------------- launch ----------------

extern "C" void kernel_launch(void* const* d_in, const int* in_sizes, int n_in,
                              void* d_out, int out_size, void* d_ws, size_t ws_size,
                              hipStream_t stream) {
    const float* x    = (const float*)d_in[0];
    const int*   eidx = (const int*)d_in[1];   // (2,E) row-major: [src | dst]
    const float* Wl1  = (const float*)d_in[2];
    const float* Wr1  = (const float*)d_in[3];
    const float* att1 = (const float*)d_in[4];
    const float* b1   = (const float*)d_in[5];
    const float* Wl2  = (const float*)d_in[6];
    const float* Wr2  = (const float*)d_in[7];
    const float* att2 = (const float*)d_in[8];
    const float* b2   = (const float*)d_in[9];
    const float* Wfc  = (const float*)d_in[10];
    const float* bfc  = (const float*)d_in[11];
    float* out = (float*)d_out;

    const int* srcv = eidx;
    const int* dstv = eidx + Ee;

    // workspace layout (~75 MB)
    size_t NHC = (size_t)Nn * HC;
    float* XR = (float*)d_ws;
    float* Hb = XR + NHC;
    float* g  = Hb + NHC;
    unsigned short* XLh = (unsigned short*)(g + HC);
    short* Ah   = (short*)(XLh + NHC);
    short* Al   = Ah + NHC;
    short* WhT1 = Al + NHC;                    // 512*256 concat [Wl|Wr]^T per layer
    short* WlT1 = WhT1 + 512 * 256;
    short* WhT2 = WlT1 + 512 * 256;
    short* WlT2 = WhT2 + 512 * 256;
    int* deg       = (int*)(WlT2 + 512 * 256);
    int* row_start = deg + Nn;
    int* cursor    = row_start + (Nn + 1);
    int* colx      = cursor + Nn;              // Ee + Nn entries
    int* bsum      = colx + (Ee + Nn);
    int* boff      = bsum + 128;               // NB+1 entries

    const int NB = (Nn + 255) / 256;           // 79
    const int N4 = (int)(NHC / 4);

    // CSR build
    init_deg<<<(Nn + 255) / 256, 256, 0, stream>>>(deg, Nn);
    hist_kernel<<<(Ee + 255) / 256, 256, 0, stream>>>(dstv, Ee, deg);
    scan1<<<NB, 256, 0, stream>>>(deg, row_start, bsum, Nn);
    scan2<<<1, 64, 0, stream>>>(bsum, boff, NB);
    scan_add<<<(Nn + 256) / 256, 256, 0, stream>>>(row_start, cursor, boff, Nn, NB);
    scatter_kernel<<<(Ee + Nn + 255) / 256, 256, 0, stream>>>(srcv, dstv, Ee, Nn, cursor, colx);

    const int GB = 157 * 8;                    // 1256 blocks, %8 == 0

    // weight prep (both layers, one dispatch) + layer-1 input split
    wsplit_all<<<1024, 256, 0, stream>>>(Wl1, Wr1, Wl2, Wr2, WhT1, WlT1, WhT2, WlT2);
    split_kernel<<<(N4 + 255) / 256, 256, 0, stream>>>(x, Ah, Al, N4);

    // layer 1 (gat writes bf16 split directly -> layer-2 GEMM input)
    mfma_gemm<<<GB, 256, 0, stream>>>(Ah, Al, WhT1, WlT1, XLh, XR);
    gat_kernel<<<Nn / 4, 256, 0, stream>>>((const ushort4*)XLh, (const float4*)XR,
                                           row_start, colx, (const float4*)att1,
                                           (const float4*)b1, (float4*)Hb,
                                           (short4*)Ah, (short4*)Al, 1);

    // layer 2
    mfma_gemm<<<GB, 256, 0, stream>>>(Ah, Al, WhT2, WlT2, XLh, XR);
    gat_kernel<<<Nn / 4, 256, 0, stream>>>((const ushort4*)XLh, (const float4*)XR,
                                           row_start, colx, (const float4*)att2,
                                           (const float4*)b2, (float4*)Hb,
                                           (short4*)Ah, (short4*)Al, 0);

    // pool + fc
    zero_f<<<1, 256, 0, stream>>>(g, HC);
    colsum_kernel<<<256, 256, 0, stream>>>(Hb, g, Nn);
    fc_kernel<<<1, 256, 0, stream>>>(g, Wfc, bfc, out, 1.0f / Nn);
}

// Round 4
// 283.445 us; speedup vs baseline: 1.3965x; 1.0342x over previous
//
#include <hip/hip_runtime.h>
#include <hip/hip_bf16.h>
#include <math.h>

#define Nn 20000
#define Ee 320000
#define INF_ 256
#define Hh 4
#define Cc 64
#define HC 256
#define NEG_SLOPE 0.2f

using frag16 = __attribute__((ext_vector_type(8))) short;   // 8 bf16 (4 VGPRs)
using f32x4  = __attribute__((ext_vector_type(4))) float;

// async global->LDS 16B per lane; LDS dest = wave-uniform base + lane*16
__device__ __forceinline__ void async16(const void* g, void* l) {
    __builtin_amdgcn_global_load_lds(
        (const __attribute__((address_space(1))) unsigned int*)g,
        (__attribute__((address_space(3))) unsigned int*)l,
        16, 0, 0);
}

// ---------------- CSR build ----------------

__global__ void init_deg(int* deg, int n) {
    int i = blockIdx.x * blockDim.x + threadIdx.x;
    if (i < n) deg[i] = 1;  // self-loop pre-counted
}

__global__ void hist_kernel(const int* __restrict__ dst, int ne, int* deg) {
    int e = blockIdx.x * blockDim.x + threadIdx.x;
    if (e < ne) atomicAdd(&deg[dst[e]], 1);
}

// hierarchical scan, phase 1: per-block (256 elems) exclusive scan + block sum
__global__ __launch_bounds__(256) void scan1(const int* __restrict__ deg,
                                             int* __restrict__ excl,
                                             int* __restrict__ bsum, int n) {
    int tid = threadIdx.x;
    int gid = blockIdx.x * 256 + tid;
    int lane = tid & 63;
    int v = (gid < n) ? deg[gid] : 0;
    int x = v;
    #pragma unroll
    for (int off = 1; off < 64; off <<= 1) {
        int y = __shfl_up(x, off, 64);
        if (lane >= off) x += y;
    }
    __shared__ int wsum[4];
    if (lane == 63) wsum[tid >> 6] = x;
    __syncthreads();
    int wadd = 0;
    for (int w = 0; w < (tid >> 6); ++w) wadd += wsum[w];
    int incl = x + wadd;
    if (gid < n) excl[gid] = incl - v;
    if (tid == 255) bsum[blockIdx.x] = incl;
}

// phase 2: single-wave scan over block sums (nb ~ 79 -> 2 iters)
__global__ void scan2(const int* __restrict__ bsum, int* __restrict__ boff, int nb) {
    int lane = threadIdx.x;
    int carry = 0;
    for (int base = 0; base < nb; base += 64) {
        int i = base + lane;
        int v = (i < nb) ? bsum[i] : 0;
        int x = v;
        #pragma unroll
        for (int off = 1; off < 64; off <<= 1) {
            int y = __shfl_up(x, off, 64);
            if (lane >= off) x += y;
        }
        if (i < nb) boff[i] = carry + x - v;
        carry += __shfl(x, 63, 64);
    }
    if (lane == 0) boff[nb] = carry;
}

// phase 3: add block offsets, produce row_start + cursor (+ total at [n])
__global__ void scan_add(int* __restrict__ row_start, int* __restrict__ cursor,
                         const int* __restrict__ boff, int n, int nb) {
    int gid = blockIdx.x * blockDim.x + threadIdx.x;
    if (gid < n) {
        int v = row_start[gid] + boff[gid >> 8];
        row_start[gid] = v;
        cursor[gid] = v;
    }
    if (gid == n) row_start[n] = boff[nb];
}

__global__ void scatter_kernel(const int* __restrict__ src, const int* __restrict__ dst,
                               int ne, int n, int* cursor, int* colx) {
    int e = blockIdx.x * blockDim.x + threadIdx.x;
    if (e < ne) {
        int d = dst[e];
        int pos = atomicAdd(&cursor[d], 1);
        colx[pos] = src[e];
    } else if (e < ne + n) {
        int node = e - ne;
        int pos = atomicAdd(&cursor[node], 1);
        colx[pos] = node;  // self-loop
    }
}

// ---------------- bf16 split-precision helpers ----------------

__device__ inline unsigned short bf16rn(float f) {
    unsigned u = __float_as_uint(f);
    unsigned r = (u + 0x7FFFu + ((u >> 16) & 1u)) >> 16;   // RTNE
    return (unsigned short)r;
}

__device__ inline void split1(float v, short& h, short& l) {
    unsigned short hh = bf16rn(v);
    float back = __uint_as_float(((unsigned)hh) << 16);
    unsigned short ll = bf16rn(v - back);
    h = (short)hh; l = (short)ll;
}

__device__ __forceinline__ float4 bf4_to_f4(ushort4 u) {
    return make_float4(__uint_as_float((unsigned)u.x << 16),
                       __uint_as_float((unsigned)u.y << 16),
                       __uint_as_float((unsigned)u.z << 16),
                       __uint_as_float((unsigned)u.w << 16));
}

// fp32 M x 256 -> hi/lo bf16 (same layout), 4 elems/thread (layer-1 x only)
__global__ __launch_bounds__(256) void split_kernel(const float* __restrict__ in,
                                                    short* __restrict__ hi,
                                                    short* __restrict__ lo, int n4) {
    int i = blockIdx.x * blockDim.x + threadIdx.x;
    if (i >= n4) return;
    float4 v = ((const float4*)in)[i];
    short4 h, l;
    split1(v.x, h.x, l.x);
    split1(v.y, h.y, l.y);
    split1(v.z, h.z, l.z);
    split1(v.w, h.w, l.w);
    ((short4*)hi)[i] = h;
    ((short4*)lo)[i] = l;
}

// all 4 weight matrices (K=256 x N=256 fp32) -> transposed split, one dispatch.
__global__ __launch_bounds__(256) void wsplit_all(const float* __restrict__ Wl1,
                                                  const float* __restrict__ Wr1,
                                                  const float* __restrict__ Wl2,
                                                  const float* __restrict__ Wr2,
                                                  short* __restrict__ WhT1,
                                                  short* __restrict__ WlT1,
                                                  short* __restrict__ WhT2,
                                                  short* __restrict__ WlT2) {
    int b = blockIdx.x;
    int n = b & 255;
    int k = threadIdx.x;
    const float* W = (b < 256) ? Wl1 : (b < 512) ? Wr1 : (b < 768) ? Wl2 : Wr2;
    short* Wh = (b < 512) ? WhT1 : WhT2;
    short* Wl = (b < 512) ? WlT1 : WlT2;
    int col = b & 511;                  // concat col within layer
    float v = W[k * 256 + n];
    short h, l;
    split1(v, h, l);
    Wh[col * 256 + k] = h;
    Wl[col * 256 + k] = l;
}

// ---------------- bf16x3 MFMA fused GEMM, single-barrier hybrid -------------
// [XL | XR] = A @ [Wl | Wr],  C = Ah*Wh + Al*Wh + Ah*Wl (bf16x3 split).
//
// Structure:
//  - B (64-col group, full K=256, hi+lo = 64 KB) staged into LDS ONCE,
//    then ONE __syncthreads. Zero barriers in the K-loop.
//  - B LDS swizzled (chunk ^= col&7) via pre-swizzled global source of
//    global_load_lds (LDS dest linear) + same XOR on ds_read -> 2-way max.
//  - A fragments loaded direct global->VGPR, K-loop fully unrolled.
//  - MFMA operands SWAPPED: mfma(b_frag, a_frag, acc) computes the transposed
//    tile, so each lane's f32x4 acc = 4 CONSECUTIVE COLUMNS of one row.
//    Epilogue becomes 8 vector stores/thread (ushort4 / float4) instead of
//    32 scalar 2B/4B stores.
//  - 24 MFMAs per K-step issued in 3 passes of 8 INDEPENDENT ops; same-acc
//    reuse distance = 8 instructions -> no dependent-MFMA stalls.
//  - XCD remap: 8 col-group blocks sharing an A row-tile run consecutively
//    on the SAME XCD -> A fetched from HBM once, re-read from local L2.

__global__ __launch_bounds__(256, 4) void mfma_gemm(const short* __restrict__ Ah,
                                                    const short* __restrict__ Al,
                                                    const short* __restrict__ WhT,
                                                    const short* __restrict__ WlT,
                                                    unsigned short* __restrict__ XLh,
                                                    float* __restrict__ XR) {
    __shared__ short BsH[64 * 256];
    __shared__ short BsL[64 * 256];

    int tid = threadIdx.x;
    int wave = tid >> 6, lane = tid & 63;
    int quad = lane >> 4, lc = lane & 15;

    // XCD-aware remap: 8 col-groups of one row-tile run consecutively on the
    // same XCD -> A fetched from HBM once, reused from local L2.
    int v = blockIdx.x;                 // 0..1255
    int p = (v & 7) * 157 + (v >> 3);
    int rowt = p >> 3;                  // 0..156
    int colg = p & 7;                   // 0..7: 64-col group of [Wl|Wr]
    int bm = rowt * 128;
    int cbase = (colg * 64) & 255;

    // ---- stage B (hi+lo) once: swizzled source, linear LDS dest ----
    {
        int cl0 = wave * 2 + (lane >> 5);          // col_local base (0..7)
        int kcs = (lane & 31) ^ (cl0 & 7);         // pre-swizzled source chunk
        const short* srcH = WhT + (size_t)(colg * 64 + cl0) * HC + kcs * 8;
        const short* srcL = WlT + (size_t)(colg * 64 + cl0) * HC + kcs * 8;
        short* dstH = &BsH[wave * 512];
        short* dstL = &BsL[wave * 512];
        #pragma unroll
        for (int r = 0; r < 8; ++r) {
            async16(srcH + (size_t)r * 8 * HC, dstH + r * 2048);
            async16(srcL + (size_t)r * 8 * HC, dstL + r * 2048);
        }
    }

    // A rows this wave owns (two 16-row sub-tiles); clamp tail rows
    int row0 = bm + wave * 32 + lc;
    int row1 = row0 + 16;
    int ca0 = (row0 < Nn) ? row0 : (Nn - 1);
    int ca1 = (row1 < Nn) ? row1 : (Nn - 1);
    const short* pa0h = Ah + (size_t)ca0 * HC + quad * 8;
    const short* pa1h = Ah + (size_t)ca1 * HC + quad * 8;
    const short* pa0l = Al + (size_t)ca0 * HC + quad * 8;
    const short* pa1l = Al + (size_t)ca1 * HC + quad * 8;

    __syncthreads();   // drains staging loads -- only barrier

    f32x4 acc[2][4] = {};
    #pragma unroll
    for (int c = 0; c < 8; ++c) {
        int k0 = c * 32;
        frag16 a0h = *(const frag16*)(pa0h + k0);
        frag16 a1h = *(const frag16*)(pa1h + k0);
        frag16 a0l = *(const frag16*)(pa0l + k0);
        frag16 a1l = *(const frag16*)(pa1l + k0);
        int sw = ((c * 4 + quad) ^ (lc & 7)) * 8;   // swizzled k-chunk (shorts)
        frag16 bh0 = *(const frag16*)&BsH[(0 * 16 + lc) * HC + sw];
        frag16 bh1 = *(const frag16*)&BsH[(1 * 16 + lc) * HC + sw];
        frag16 bh2 = *(const frag16*)&BsH[(2 * 16 + lc) * HC + sw];
        frag16 bh3 = *(const frag16*)&BsH[(3 * 16 + lc) * HC + sw];
        frag16 bl0 = *(const frag16*)&BsL[(0 * 16 + lc) * HC + sw];
        frag16 bl1 = *(const frag16*)&BsL[(1 * 16 + lc) * HC + sw];
        frag16 bl2 = *(const frag16*)&BsL[(2 * 16 + lc) * HC + sw];
        frag16 bl3 = *(const frag16*)&BsL[(3 * 16 + lc) * HC + sw];
        // pass 1: Ah*Wh  (8 independent MFMAs)
        acc[0][0] = __builtin_amdgcn_mfma_f32_16x16x32_bf16(bh0, a0h, acc[0][0], 0, 0, 0);
        acc[1][0] = __builtin_amdgcn_mfma_f32_16x16x32_bf16(bh0, a1h, acc[1][0], 0, 0, 0);
        acc[0][1] = __builtin_amdgcn_mfma_f32_16x16x32_bf16(bh1, a0h, acc[0][1], 0, 0, 0);
        acc[1][1] = __builtin_amdgcn_mfma_f32_16x16x32_bf16(bh1, a1h, acc[1][1], 0, 0, 0);
        acc[0][2] = __builtin_amdgcn_mfma_f32_16x16x32_bf16(bh2, a0h, acc[0][2], 0, 0, 0);
        acc[1][2] = __builtin_amdgcn_mfma_f32_16x16x32_bf16(bh2, a1h, acc[1][2], 0, 0, 0);
        acc[0][3] = __builtin_amdgcn_mfma_f32_16x16x32_bf16(bh3, a0h, acc[0][3], 0, 0, 0);
        acc[1][3] = __builtin_amdgcn_mfma_f32_16x16x32_bf16(bh3, a1h, acc[1][3], 0, 0, 0);
        // pass 2: Al*Wh  (reuse distance 8 from pass 1)
        acc[0][0] = __builtin_amdgcn_mfma_f32_16x16x32_bf16(bh0, a0l, acc[0][0], 0, 0, 0);
        acc[1][0] = __builtin_amdgcn_mfma_f32_16x16x32_bf16(bh0, a1l, acc[1][0], 0, 0, 0);
        acc[0][1] = __builtin_amdgcn_mfma_f32_16x16x32_bf16(bh1, a0l, acc[0][1], 0, 0, 0);
        acc[1][1] = __builtin_amdgcn_mfma_f32_16x16x32_bf16(bh1, a1l, acc[1][1], 0, 0, 0);
        acc[0][2] = __builtin_amdgcn_mfma_f32_16x16x32_bf16(bh2, a0l, acc[0][2], 0, 0, 0);
        acc[1][2] = __builtin_amdgcn_mfma_f32_16x16x32_bf16(bh2, a1l, acc[1][2], 0, 0, 0);
        acc[0][3] = __builtin_amdgcn_mfma_f32_16x16x32_bf16(bh3, a0l, acc[0][3], 0, 0, 0);
        acc[1][3] = __builtin_amdgcn_mfma_f32_16x16x32_bf16(bh3, a1l, acc[1][3], 0, 0, 0);
        // pass 3: Ah*Wl
        acc[0][0] = __builtin_amdgcn_mfma_f32_16x16x32_bf16(bl0, a0h, acc[0][0], 0, 0, 0);
        acc[1][0] = __builtin_amdgcn_mfma_f32_16x16x32_bf16(bl0, a1h, acc[1][0], 0, 0, 0);
        acc[0][1] = __builtin_amdgcn_mfma_f32_16x16x32_bf16(bl1, a0h, acc[0][1], 0, 0, 0);
        acc[1][1] = __builtin_amdgcn_mfma_f32_16x16x32_bf16(bl1, a1h, acc[1][1], 0, 0, 0);
        acc[0][2] = __builtin_amdgcn_mfma_f32_16x16x32_bf16(bl2, a0h, acc[0][2], 0, 0, 0);
        acc[1][2] = __builtin_amdgcn_mfma_f32_16x16x32_bf16(bl2, a1h, acc[1][2], 0, 0, 0);
        acc[0][3] = __builtin_amdgcn_mfma_f32_16x16x32_bf16(bl3, a0h, acc[0][3], 0, 0, 0);
        acc[1][3] = __builtin_amdgcn_mfma_f32_16x16x32_bf16(bl3, a1h, acc[1][3], 0, 0, 0);
    }

    // transposed C-layout epilogue: lane (quad,lc) holds row (..+lc),
    // cols (cbase + t*16 + quad*4 .. +3) -> vector stores.
    #pragma unroll
    for (int mt = 0; mt < 2; ++mt) {
        int rw = bm + wave * 32 + mt * 16 + lc;
        if (rw >= Nn) continue;
        #pragma unroll
        for (int t = 0; t < 4; ++t) {
            int col0 = cbase + t * 16 + quad * 4;
            if (colg < 4) {
                ushort4 o;
                o.x = bf16rn(acc[mt][t][0]);
                o.y = bf16rn(acc[mt][t][1]);
                o.z = bf16rn(acc[mt][t][2]);
                o.w = bf16rn(acc[mt][t][3]);
                *(ushort4*)&XLh[(size_t)rw * HC + col0] = o;
            } else {
                *(f32x4*)&XR[(size_t)rw * HC + col0] = acc[mt][t];
            }
        }
    }
}

// ---------------- GATv2 edge phase ----------------
// One wave per node (4 nodes/block). Lane holds 4 channels; head h = lanes
// 16h..16h+15. XL gathered in bf16 (8 B/lane); XR/bias fp32.
// No-max softmax (scores bounded << 88); leaky(t)=0.6t+0.4|t|.
// Edge list walked pairwise with scalar colx loads and next-pair index
// prefetch, so gathers issue back-to-back.
// mode 1: also write bf16 hi/lo split of relu(h) for next layer's GEMM.

__device__ __forceinline__ float edge_score(const float4 v, const float4 xr,
                                            const float4 a06, const float4 a04) {
    float tx = v.x + xr.x, ty = v.y + xr.y, tz = v.z + xr.z, tw = v.w + xr.w;
    float p = a06.x * tx + a04.x * fabsf(tx);
    p += a06.y * ty + a04.y * fabsf(ty);
    p += a06.z * tz + a04.z * fabsf(tz);
    p += a06.w * tw + a04.w * fabsf(tw);
    p += __shfl_xor(p, 1, 64);
    p += __shfl_xor(p, 2, 64);
    p += __shfl_xor(p, 4, 64);
    p += __shfl_xor(p, 8, 64);             // per-head score in its 16 lanes
    return p;
}

__global__ __launch_bounds__(256) void gat_kernel(const ushort4* __restrict__ XL4,
                                                  const float4* __restrict__ XR4,
                                                  const int* __restrict__ row_start,
                                                  const int* __restrict__ colx,
                                                  const float4* __restrict__ att4,
                                                  const float4* __restrict__ bias4,
                                                  float4* __restrict__ Hout,
                                                  short4* __restrict__ Ahi,
                                                  short4* __restrict__ Alo,
                                                  int mode) {
    int wave = threadIdx.x >> 6, lane = threadIdx.x & 63;
    int node = blockIdx.x * 4 + wave;          // grid = Nn/4 exactly
    float4 xr = XR4[(size_t)node * 64 + lane];
    float4 a  = att4[lane];
    float4 a06 = make_float4(a.x * 0.6f, a.y * 0.6f, a.z * 0.6f, a.w * 0.6f);
    float4 a04 = make_float4(a.x * 0.4f, a.y * 0.4f, a.z * 0.4f, a.w * 0.4f);
    int e0 = __builtin_amdgcn_readfirstlane(row_start[node]);
    int e1 = __builtin_amdgcn_readfirstlane(row_start[node + 1]);
    float l0 = 0.f, l1 = 0.f;
    float4 acc0 = make_float4(0.f, 0.f, 0.f, 0.f);
    float4 acc1 = make_float4(0.f, 0.f, 0.f, 0.f);
    int npairs = (e1 - e0) >> 1;
    int e = e0;
    int s0 = 0, s1 = 0;
    if (npairs > 0) { s0 = colx[e]; s1 = colx[e + 1]; }    // scalar loads
    for (int pp = 0; pp < npairs; ++pp) {
        int en = e + 2;
        int i0 = (en     < e1) ? en     : (e1 - 1);
        int i1 = (en + 1 < e1) ? en + 1 : (e1 - 1);
        int ns0 = colx[i0];                   // prefetch next pair (scalar)
        int ns1 = colx[i1];
        ushort4 u0 = XL4[(size_t)s0 * 64 + lane];
        ushort4 u1 = XL4[(size_t)s1 * 64 + lane];
        float4 v0 = bf4_to_f4(u0);
        float4 v1 = bf4_to_f4(u1);
        float pe0 = __expf(edge_score(v0, xr, a06, a04));
        float pe1 = __expf(edge_score(v1, xr, a06, a04));
        l0 += pe0; l1 += pe1;
        acc0.x += pe0 * v0.x; acc0.y += pe0 * v0.y;
        acc0.z += pe0 * v0.z; acc0.w += pe0 * v0.w;
        acc1.x += pe1 * v1.x; acc1.y += pe1 * v1.y;
        acc1.z += pe1 * v1.z; acc1.w += pe1 * v1.w;
        s0 = ns0; s1 = ns1; e = en;
    }
    if (e < e1) {                              // odd tail edge
        int st = colx[e];
        float4 v0 = bf4_to_f4(XL4[(size_t)st * 64 + lane]);
        float pe0 = __expf(edge_score(v0, xr, a06, a04));
        l0 += pe0;
        acc0.x += pe0 * v0.x; acc0.y += pe0 * v0.y;
        acc0.z += pe0 * v0.z; acc0.w += pe0 * v0.w;
    }
    float rl = 1.f / (l0 + l1);
    float4 b = bias4[lane];
    float4 o = make_float4(fmaxf((acc0.x + acc1.x) * rl + b.x, 0.f),
                           fmaxf((acc0.y + acc1.y) * rl + b.y, 0.f),
                           fmaxf((acc0.z + acc1.z) * rl + b.z, 0.f),
                           fmaxf((acc0.w + acc1.w) * rl + b.w, 0.f));
    size_t oidx = (size_t)node * 64 + lane;
    if (mode) {
        short4 h4, l4;
        split1(o.x, h4.x, l4.x);
        split1(o.y, h4.y, l4.y);
        split1(o.z, h4.z, l4.z);
        split1(o.w, h4.w, l4.w);
        Ahi[oidx] = h4;
        Alo[oidx] = l4;
    } else {
        Hout[oidx] = o;
    }
}

// ---------------- pooling + FC ----------------

__global__ void zero_f(float* p, int n) {
    int i = blockIdx.x * blockDim.x + threadIdx.x;
    if (i < n) p[i] = 0.f;
}

__global__ __launch_bounds__(256) void colsum_kernel(const float* __restrict__ Hmat,
                                                     float* __restrict__ g, int n) {
    int ch = threadIdx.x;
    float s = 0.f;
    for (int r = blockIdx.x; r < n; r += gridDim.x)
        s += Hmat[(size_t)r * HC + ch];
    atomicAdd(&g[ch], s);
}

__global__ __launch_bounds__(256) void fc_kernel(const float* __restrict__ g,
                                                 const float* __restrict__ Wfc,
                                                 const float* __restrict__ bfc,
                                                 float* __restrict__ out, float invN) {
    int t = threadIdx.x;
    float gv = g[t] * invN;
    float p0 = gv * Wfc[2 * t];
    float p1 = gv * Wfc[2 * t + 1];
    #pragma unroll
    for (int off = 32; off > 0; off >>= 1) {
        p0 += __shfl_xor(p0, off, 64);
        p1 += __shfl_xor(p1, off, 64);
    }
    __shared__ float s0[4], s1[4];
    if ((t & 63) == 0) { s0[t >> 6] = p0; s1[t >> 6] = p1; }
    __syncthreads();
    if (t == 0) {
        out[0] = s0[0] + s0[1] + s0[2] + s0[3] + bfc[0];
        out[1] = s1[0] + s1[1] + s1[2] + s1[3] + bfc[1];
    }
}

// ---------------- launch ----------------

extern "C" void kernel_launch(void* const* d_in, const int* in_sizes, int n_in,
                              void* d_out, int out_size, void* d_ws, size_t ws_size,
                              hipStream_t stream) {
    const float* x    = (const float*)d_in[0];
    const int*   eidx = (const int*)d_in[1];   // (2,E) row-major: [src | dst]
    const float* Wl1  = (const float*)d_in[2];
    const float* Wr1  = (const float*)d_in[3];
    const float* att1 = (const float*)d_in[4];
    const float* b1   = (const float*)d_in[5];
    const float* Wl2  = (const float*)d_in[6];
    const float* Wr2  = (const float*)d_in[7];
    const float* att2 = (const float*)d_in[8];
    const float* b2   = (const float*)d_in[9];
    const float* Wfc  = (const float*)d_in[10];
    const float* bfc  = (const float*)d_in[11];
    float* out = (float*)d_out;

    const int* srcv = eidx;
    const int* dstv = eidx + Ee;

    // workspace layout (~75 MB)
    size_t NHC = (size_t)Nn * HC;
    float* XR = (float*)d_ws;
    float* Hb = XR + NHC;
    float* g  = Hb + NHC;
    unsigned short* XLh = (unsigned short*)(g + HC);
    short* Ah   = (short*)(XLh + NHC);
    short* Al   = Ah + NHC;
    short* WhT1 = Al + NHC;                    // 512*256 concat [Wl|Wr]^T per layer
    short* WlT1 = WhT1 + 512 * 256;
    short* WhT2 = WlT1 + 512 * 256;
    short* WlT2 = WhT2 + 512 * 256;
    int* deg       = (int*)(WlT2 + 512 * 256);
    int* row_start = deg + Nn;
    int* cursor    = row_start + (Nn + 1);
    int* colx      = cursor + Nn;              // Ee + Nn entries
    int* bsum      = colx + (Ee + Nn);
    int* boff      = bsum + 128;               // NB+1 entries

    const int NB = (Nn + 255) / 256;           // 79
    const int N4 = (int)(NHC / 4);

    // CSR build
    init_deg<<<(Nn + 255) / 256, 256, 0, stream>>>(deg, Nn);
    hist_kernel<<<(Ee + 255) / 256, 256, 0, stream>>>(dstv, Ee, deg);
    scan1<<<NB, 256, 0, stream>>>(deg, row_start, bsum, Nn);
    scan2<<<1, 64, 0, stream>>>(bsum, boff, NB);
    scan_add<<<(Nn + 256) / 256, 256, 0, stream>>>(row_start, cursor, boff, Nn, NB);
    scatter_kernel<<<(Ee + Nn + 255) / 256, 256, 0, stream>>>(srcv, dstv, Ee, Nn, cursor, colx);

    const int GB = 157 * 8;                    // 1256 blocks, %8 == 0

    // weight prep (both layers, one dispatch) + layer-1 input split
    wsplit_all<<<1024, 256, 0, stream>>>(Wl1, Wr1, Wl2, Wr2, WhT1, WlT1, WhT2, WlT2);
    split_kernel<<<(N4 + 255) / 256, 256, 0, stream>>>(x, Ah, Al, N4);

    // layer 1 (gat writes bf16 split directly -> layer-2 GEMM input)
    mfma_gemm<<<GB, 256, 0, stream>>>(Ah, Al, WhT1, WlT1, XLh, XR);
    gat_kernel<<<Nn / 4, 256, 0, stream>>>((const ushort4*)XLh, (const float4*)XR,
                                           row_start, colx, (const float4*)att1,
                                           (const float4*)b1, (float4*)Hb,
                                           (short4*)Ah, (short4*)Al, 1);

    // layer 2
    mfma_gemm<<<GB, 256, 0, stream>>>(Ah, Al, WhT2, WlT2, XLh, XR);
    gat_kernel<<<Nn / 4, 256, 0, stream>>>((const ushort4*)XLh, (const float4*)XR,
                                           row_start, colx, (const float4*)att2,
                                           (const float4*)b2, (float4*)Hb,
                                           (short4*)Ah, (short4*)Al, 0);

    // pool + fc
    zero_f<<<1, 256, 0, stream>>>(g, HC);
    colsum_kernel<<<256, 256, 0, stream>>>(Hb, g, Nn);
    fc_kernel<<<1, 256, 0, stream>>>(g, Wfc, bfc, out, 1.0f / Nn);
}